// Round 9
// baseline (119.771 us; speedup 1.0000x reference)
//
#include <hip/hip_runtime.h>

// B=128, K=256, M=8, D=128 ; rows = B*K = 32768 flattened (b,k)
#define LT 20.0f        // lambda == gamma == 20
#define CHUNKS 16       // 16 chunks x 128 cols = all 2048 prototype columns
#define NBLK 512        // 512 blocks x 64 rows = all 32768 rows

typedef _Float16 half8 __attribute__((ext_vector_type(8)));
typedef float    f32x4 __attribute__((ext_vector_type(4)));

__device__ __forceinline__ float swz16(float x) {
    // xor lane^16 within 32-lane halves (BitMode: xor=16, and=0x1F)
    return __int_as_float(__builtin_amdgcn_ds_swizzle(__float_as_int(x), 0x401F));
}

// async global->LDS, 16B per lane; lds base must be wave-uniform
#define GLD16(gp, lp) __builtin_amdgcn_global_load_lds( \
    (const __attribute__((address_space(1))) void*)(gp), \
    (__attribute__((address_space(3))) void*)(lp), 16, 0, 0)

// explicit per-wave drain of outstanding global_load_lds DMA before a barrier.
// Theory: at 2 blocks/CU the compiler-emitted drain is absent/insufficient and
// consumers race the DMA LDS-write (rounds 6-8 nondeterministic corruption).
#define VM_DRAIN() asm volatile("s_waitcnt vmcnt(0)" ::: "memory")

// ---- prep: pack P f32->f16 swizzled — byte-identical to round 5 (verified) ----
__global__ __launch_bounds__(256)
void mpcl_prep(const float* __restrict__ P, _Float16* __restrict__ Pw)
{
    int id   = blockIdx.x * 256 + threadIdx.x;   // 0..32767
    int gcol = id >> 4;                          // P row (concept*8+m)
    int dblk = id & 15;                          // d/8
    int ch   = gcol >> 7;
    int col  = gcol & 127;
    int key  = (col & 3) | ((col & 8) >> 1);
    int dbs  = (dblk & 8) | ((dblk ^ key) & 7);
    const float* src = P + (size_t)gcol * 128 + dblk * 8;
    float4 a = *(const float4*)src;
    float4 b = *(const float4*)(src + 4);
    half8 hv;
    hv[0] = (_Float16)a.x; hv[1] = (_Float16)a.y;
    hv[2] = (_Float16)a.z; hv[3] = (_Float16)a.w;
    hv[4] = (_Float16)b.x; hv[5] = (_Float16)b.y;
    hv[6] = (_Float16)b.z; hv[7] = (_Float16)b.w;
    *(half8*)&Pw[((size_t)ch * 2048 + col * 16 + dbs) * 8] = hv;
}

// Grid: 512 blocks x 512 thr (8 waves) => 2 blocks/CU (LDS 66 KB/block).
// Block owns 64 contiguous rows x all 2048 cols.
// wave w: rg=w>>2 (0..1) -> 32 rows (rf 0..1 x 16); colq=w&3 -> 4 concepts/chunk.
// MFMA pair trick (round-5-verified): A1 = protos 0-3 of 4 concepts, A2 = protos 4-7;
// lane (q,n) ends with all 8 protos of concept colq*4+q for V-row n in acc1+acc2.
__global__ __launch_bounds__(512)
void mpcl_main(const float* __restrict__ V,        // (32768, 128)
               const int*   __restrict__ labels,   // (32768)
               const _Float16* __restrict__ Pw,    // packed P
               int* __restrict__ gcnt, float* __restrict__ gsum,
               float* __restrict__ out)
{
    __shared__ __align__(16) _Float16 Pst[2][16384];   // 2 x 32 KB double buffer
    __shared__ float sh_denom[64];
    __shared__ float sh_simpos[64];

    const int tid  = threadIdx.x;
    const int lane = tid & 63;
    const int w    = tid >> 6;        // 0..7
    const int rg   = w >> 2;          // 0..1 -> 32-row group
    const int colq = w & 3;           // 0..3 -> 4-concept group per chunk
    const int n    = lane & 15;
    const int q    = lane >> 4;
    const int rowbase = blockIdx.x * 64;

    if (tid < 64) { sh_denom[tid] = 0.0f; sh_simpos[tid] = 0.0f; }

    // ---- V fragments (B operand), f16, register-resident (round-5 mapping) ----
    half8 vh[2][4];
#pragma unroll
    for (int rf = 0; rf < 2; ++rf) {
        const float* vr = V + (size_t)(rowbase + rg * 32 + rf * 16 + n) * 128 + q * 8;
#pragma unroll
        for (int c = 0; c < 4; ++c) {
            float4 x0 = *(const float4*)(vr + c * 32);
            float4 x1 = *(const float4*)(vr + c * 32 + 4);
            vh[rf][c][0] = (_Float16)x0.x; vh[rf][c][1] = (_Float16)x0.y;
            vh[rf][c][2] = (_Float16)x0.z; vh[rf][c][3] = (_Float16)x0.w;
            vh[rf][c][4] = (_Float16)x1.x; vh[rf][c][5] = (_Float16)x1.y;
            vh[rf][c][6] = (_Float16)x1.z; vh[rf][c][7] = (_Float16)x1.w;
        }
    }

    // ---- A-fragment LDS offsets (verified round-5 layout) ----
    const int col1 = colq * 32 + ((n >> 2) << 3) + (n & 3);
    int off1[4];
#pragma unroll
    for (int c = 0; c < 4; ++c) {
        int dblk = c * 4 + q;
        int dbs  = (dblk & 8) | ((dblk ^ (n & 7)) & 7);
        off1[c]  = (col1 * 16 + dbs) * 8;
    }

    // ---- staging: 8 waves x 4 GLD16; wave w covers halves [w*2048,(w+1)*2048)
    // of each 16384-half chunk — identity copy of the packed Pw layout.
    const _Float16* gb = Pw + (size_t)w * 2048 + (size_t)lane * 8;
    _Float16* l0 = &Pst[0][w * 2048];
    _Float16* l1 = &Pst[1][w * 2048];
#pragma unroll
    for (int s = 0; s < 4; ++s) GLD16(gb + s * 512, l0 + s * 512);   // chunk 0

    const int rowk0 = (rowbase + rg * 32 + n) & 255;        // positive concept, rf=0
    const int rowk1 = (rowbase + rg * 32 + 16 + n) & 255;   // rf=1

    float dn[2] = {0.f, 0.f};

#pragma unroll 1
    for (int ch = 0; ch < CHUNKS; ++ch) {
        VM_DRAIN();        // this wave's staged DMA for chunk ch has landed in LDS
        __syncthreads();   // all waves' staging visible; prev buffer free

        if (ch < CHUNKS - 1) {   // fire next chunk's loads into the other buffer
            const _Float16* g = gb + (size_t)(ch + 1) * 16384;
            _Float16* lnx = (ch & 1) ? l0 : l1;
#pragma unroll
            for (int s = 0; s < 4; ++s) GLD16(g + s * 512, lnx + s * 512);
        }

        const _Float16* base = (ch & 1) ? &Pst[1][0] : &Pst[0][0];

        f32x4 acc1[2] = {{0.f,0.f,0.f,0.f},{0.f,0.f,0.f,0.f}};
        f32x4 acc2[2] = {{0.f,0.f,0.f,0.f},{0.f,0.f,0.f,0.f}};
#pragma unroll
        for (int c = 0; c < 4; ++c) {
            half8 a1 = *(const half8*)&base[off1[c]];
            half8 a2 = *(const half8*)&base[off1[c] + 512];   // col+4
            acc1[0] = __builtin_amdgcn_mfma_f32_16x16x32_f16(a1, vh[0][c], acc1[0], 0, 0, 0);
            acc1[1] = __builtin_amdgcn_mfma_f32_16x16x32_f16(a1, vh[1][c], acc1[1], 0, 0, 0);
            acc2[0] = __builtin_amdgcn_mfma_f32_16x16x32_f16(a2, vh[0][c], acc2[0], 0, 0, 0);
            acc2[1] = __builtin_amdgcn_mfma_f32_16x16x32_f16(a2, vh[1][c], acc2[1], 0, 0, 0);
        }

        // ---- in-lane softmax over each concept's 8 protos (round-5 epilogue) ----
        const int cA = ch * 16 + colq * 4 + q;
#pragma unroll
        for (int rf = 0; rf < 2; ++rf) {
            float x0 = fminf(fmaxf(acc1[rf][0], -4.f), 4.f), x1 = fminf(fmaxf(acc1[rf][1], -4.f), 4.f);
            float x2 = fminf(fmaxf(acc1[rf][2], -4.f), 4.f), x3 = fminf(fmaxf(acc1[rf][3], -4.f), 4.f);
            float x4 = fminf(fmaxf(acc2[rf][0], -4.f), 4.f), x5 = fminf(fmaxf(acc2[rf][1], -4.f), 4.f);
            float x6 = fminf(fmaxf(acc2[rf][2], -4.f), 4.f), x7 = fminf(fmaxf(acc2[rf][3], -4.f), 4.f);
            float e0 = __expf(LT * x0), e1 = __expf(LT * x1);
            float e2 = __expf(LT * x2), e3 = __expf(LT * x3);
            float e4 = __expf(LT * x4), e5 = __expf(LT * x5);
            float e6 = __expf(LT * x6), e7 = __expf(LT * x7);
            float es = ((e0 + e1) + (e2 + e3)) + ((e4 + e5) + (e6 + e7));
            float ss = fmaf(e0, x0, fmaf(e1, x1, fmaf(e2, x2, e3 * x3)))
                     + fmaf(e4, x4, fmaf(e5, x5, fmaf(e6, x6, e7 * x7)));
            float simc = __fdividef(ss, es);
            dn[rf] += __expf(LT * simc);
            if (cA == (rf ? rowk1 : rowk0))
                sh_simpos[rg * 32 + rf * 16 + n] = simc;   // unique writer per row
        }
    }

    // ---- fold denominators over the 4 q-groups (distinct concepts) ----
#pragma unroll
    for (int rf = 0; rf < 2; ++rf) {
        float t = dn[rf];
        t += swz16(t);
        t += __shfl_xor(t, 32);
        if (lane < 16)
            atomicAdd(&sh_denom[rg * 32 + rf * 16 + n], t);
    }
    __syncthreads();

    // ---- in-block loss over 64 rows, one global atomic per block ----
    if (tid < 64) {
        int row = rowbase + tid;
        float lp = logf(sh_denom[tid] + 1e-8f) - LT * (sh_simpos[tid] + 0.05f);
        float mk = (labels[row] == 1) ? 1.0f : 0.0f;
        float s  = lp * mk;
        float cc = mk;
#pragma unroll
        for (int off = 32; off >= 1; off >>= 1) {
            s  += __shfl_down(s, off);
            cc += __shfl_down(cc, off);
        }
        if (lane == 0) {
            atomicAdd(&gsum[0], s);
            atomicAdd(&gsum[1], cc);
        }
    }

    // ---- all NBLK blocks arrive; last one finalizes ----
    if (tid == 0) {
        __threadfence();
        int g = __hip_atomic_fetch_add(gcnt, 1,
                                       __ATOMIC_ACQ_REL, __HIP_MEMORY_SCOPE_AGENT);
        if (g == NBLK - 1) {
            __threadfence();
            float ts = __hip_atomic_load(&gsum[0], __ATOMIC_RELAXED, __HIP_MEMORY_SCOPE_AGENT);
            float tc = __hip_atomic_load(&gsum[1], __ATOMIC_RELAXED, __HIP_MEMORY_SCOPE_AGENT);
            out[0] = (tc > 0.0f) ? (ts / tc) : ts;
        }
    }
}

extern "C" void kernel_launch(void* const* d_in, const int* in_sizes, int n_in,
                              void* d_out, int out_size, void* d_ws, size_t ws_size,
                              hipStream_t stream)
{
    const float* V      = (const float*)d_in[0];
    const int*   labels = (const int*)d_in[1];
    const float* P      = (const float*)d_in[2];
    float* out = (float*)d_out;

    // ws layout — byte-identical footprint to the PASSING round-5 kernel:
    // [0,64) counters (gcnt@0, gsum@8); Pw f16 packed P at [64, 524352).
    int*   wsi  = (int*)d_ws;
    int*   gcnt = wsi;
    float* gsum = (float*)(wsi + 2);
    _Float16* Pw = (_Float16*)((char*)d_ws + 64);

    hipMemsetAsync(d_ws, 0, 64, stream);
    mpcl_prep<<<128, 256, 0, stream>>>(P, Pw);
    mpcl_main<<<NBLK, 512, 0, stream>>>(V, labels, Pw, gcnt, gsum, out);
}